// Round 1
// 402.677 us; speedup vs baseline: 1.0943x; 1.0943x over previous
//
#include <hip/hip_runtime.h>
#include <math.h>

#define S_LEN 2048
#define DMODEL 1024
#define NHEAD 16
#define HDIM 64

typedef unsigned short ushort_t;
typedef __attribute__((ext_vector_type(8))) short short8;
typedef __attribute__((ext_vector_type(4))) float floatx4;
typedef __attribute__((ext_vector_type(4))) unsigned short ushort4v;
typedef __attribute__((ext_vector_type(2))) unsigned short ushort2v;

typedef __attribute__((address_space(3))) unsigned int lds_uint;
typedef const __attribute__((address_space(1))) unsigned int gbl_uint;

__device__ __forceinline__ float b2f(ushort_t u) {
  return __uint_as_float(((unsigned)u) << 16);
}
__device__ __forceinline__ ushort_t f2b(float x) {
  unsigned u = __float_as_uint(x);
  return (ushort_t)((u + 0x7fffu + ((u >> 16) & 1u)) >> 16);
}
__device__ __forceinline__ void gld16(const void* g, void* l) {
  __builtin_amdgcn_global_load_lds((gbl_uint*)g, (lds_uint*)l, 16, 0, 0);
}

// ---------------------------------------------------------------------------
// Dtype detection: 1 = bf16 inputs, 0 = fp32 inputs.
// ---------------------------------------------------------------------------
__global__ __launch_bounds__(256) void detect_kernel(
    const unsigned* __restrict__ q, int* __restrict__ flag) {
  __shared__ int cnt[256];
  int c = 0;
#pragma unroll
  for (int i = 0; i < 16; ++i) {
    const unsigned w = q[threadIdx.x * 16 + i];
    const unsigned e = (w >> 7) & 0xFFu;
    c += (e >= 112u && e <= 135u) ? 1 : 0;
  }
  cnt[threadIdx.x] = c;
  __syncthreads();
  if (threadIdx.x == 0) {
    int t = 0;
    for (int i = 0; i < 256; ++i) t += cnt[i];
    *flag = (t > 2048) ? 1 : 0;
  }
}

// ---------------------------------------------------------------------------
// Biases -> fp32 ws buffer [4][1024] in order q,k,v,o
// ---------------------------------------------------------------------------
__global__ __launch_bounds__(256) void bias_kernel(
    const void* __restrict__ bq, const void* __restrict__ bk,
    const void* __restrict__ bv, const void* __restrict__ bo,
    const int* __restrict__ flag, float* __restrict__ out) {
  const int i = blockIdx.x * 256 + threadIdx.x;
  const int z = i >> 10;
  const void* src = z == 0 ? bq : z == 1 ? bk : z == 2 ? bv : bo;
  const int j = i & 1023;
  const float v = (*flag) ? b2f(((const ushort_t*)src)[j])
                          : ((const float*)src)[j];
  out[i] = v;
}

// ---------------------------------------------------------------------------
// Weight transpose (either dtype) -> bf16 Wt[n][k], 4 weights
// ---------------------------------------------------------------------------
__global__ __launch_bounds__(256) void wtrans_kernel(
    const void* __restrict__ Wq, const void* __restrict__ Wk,
    const void* __restrict__ Wv, const void* __restrict__ Wo,
    const int* __restrict__ flag, ushort_t* __restrict__ Wt) {
  __shared__ float t[32][33];
  const void* src = blockIdx.z == 0 ? Wq : blockIdx.z == 1 ? Wk
                    : blockIdx.z == 2 ? Wv : Wo;
  ushort_t* dst = Wt + (size_t)blockIdx.z * (DMODEL * (size_t)DMODEL);
  const int isbf = *flag;
  const int tx = threadIdx.x & 31, ty = threadIdx.x >> 5;
  const int bx = blockIdx.x * 32, by = blockIdx.y * 32;
#pragma unroll
  for (int i = 0; i < 4; ++i) {
    const size_t idx = (size_t)(by + ty + 8 * i) * DMODEL + bx + tx;
    t[ty + 8 * i][tx] = isbf ? b2f(((const ushort_t*)src)[idx])
                             : ((const float*)src)[idx];
  }
  __syncthreads();
#pragma unroll
  for (int i = 0; i < 4; ++i)
    dst[(size_t)(bx + ty + 8 * i) * DMODEL + by + tx] = f2b(t[tx][ty + 8 * i]);
}

// ---------------------------------------------------------------------------
// NEW: input activation convert (fp32 -> bf16, or bf16 copy) -> Abf[z][8192][1024]
// grid (4096, 3), block 256; one short8 (8 elems) per thread.
// ---------------------------------------------------------------------------
__global__ __launch_bounds__(256) void convert_kernel(
    const void* __restrict__ q, const void* __restrict__ k,
    const void* __restrict__ v, const int* __restrict__ flag,
    ushort_t* __restrict__ Abf) {
  const int z = blockIdx.y;
  const void* src = z == 0 ? q : z == 1 ? k : v;
  ushort_t* dst = Abf + (size_t)z * (8192 * (size_t)DMODEL);
  const size_t i = (size_t)blockIdx.x * 256 + threadIdx.x;  // vec8 index
  short8 o;
  if (*flag) {
    o = ((const short8*)src)[i];
  } else {
    const floatx4 a = ((const floatx4*)src)[2 * i];
    const floatx4 b = ((const floatx4*)src)[2 * i + 1];
    o[0] = (short)f2b(a.x); o[1] = (short)f2b(a.y);
    o[2] = (short)f2b(a.z); o[3] = (short)f2b(a.w);
    o[4] = (short)f2b(b.x); o[5] = (short)f2b(b.y);
    o[6] = (short)f2b(b.z); o[7] = (short)f2b(b.w);
  }
  ((short8*)dst)[i] = o;
}

// ---------------------------------------------------------------------------
// NEW: 256x256 / BK=64 / 8-wave GEMM core with 4-phase counted-vmcnt schedule.
// A[m][k], Bm[n][k] bf16, K=1024 (16 K-tiles, double-buffered LDS, 128 KiB).
// Per phase: {ds_read frags | stage one half-tile via global_load_lds} ->
// barrier -> setprio(1) 16xMFMA setprio(0) -> counted vmcnt -> barrier.
// Staging runs exactly one K-tile ahead; steady-state waits are vmcnt(6)/
// vmcnt(6)/vmcnt(4) (never 0). LDS xor-swizzle (16B block ^ (row&7)) keeps
// ds_read_b128 conflict-free (same scheme as the verified 128^2 kernel).
// ---------------------------------------------------------------------------
__device__ __forceinline__ void gemm256_core(
    const ushort_t* __restrict__ A, const ushort_t* __restrict__ Bm,
    const int m0, const int n0, ushort_t* smem, floatx4 acc[8][4]) {
  const int tid = threadIdx.x;
  const int w = tid >> 6, l = tid & 63;
  const int wr = w >> 2, wc = w & 3;
  const int lm = l & 15, lg = l >> 4;
  const int lr8 = l >> 3, lc8 = l & 7;
  const int gblk = lc8 ^ lr8;

  ushort_t* Ab = smem;            // [2][256][64]
  ushort_t* Bb = smem + 32768;    // [2][256][64]

  const ushort_t* Ag = A + (size_t)(m0 + w * 16 + lr8) * DMODEL + gblk * 8;
  const ushort_t* Bg = Bm + (size_t)(n0 + w * 16 + lr8) * DMODEL + gblk * 8;
  ushort_t* Asw = Ab + (w * 16) * 64;  // wave-uniform LDS stage base
  ushort_t* Bsw = Bb + (w * 16) * 64;

  const int swz = lm & 7;
  const int cK0 = ((0 + lg) ^ swz) * 8;
  const int cK1 = ((4 + lg) ^ swz) * 8;

  short8 af[4][2], bf0[2][2], bf1[2][2];

#define FENCE asm volatile("" ::: "memory")
#define BAR                        \
  do {                             \
    FENCE;                         \
    __builtin_amdgcn_s_barrier();  \
    FENCE;                         \
  } while (0)
#define STG(gp, lp, h, ko)                                                    \
  do {                                                                        \
    gld16((gp) + (size_t)((h) * 128) * DMODEL + (ko),                         \
          (lp) + ((h) * 128) * 64);                                           \
    gld16((gp) + (size_t)((h) * 128 + 8) * DMODEL + (ko),                     \
          (lp) + ((h) * 128 + 8) * 64);                                       \
  } while (0)
#define LDA(mh, co)                                                           \
  do {                                                                        \
    _Pragma("unroll") for (int f = 0; f < 4; ++f) {                           \
      const int ra = (co) + (wr * 128 + (mh) * 64 + f * 16 + lm) * 64;        \
      af[f][0] = *(const short8*)&Ab[ra + cK0];                               \
      af[f][1] = *(const short8*)&Ab[ra + cK1];                               \
    }                                                                         \
  } while (0)
#define LDB(bfx, nh, co)                                                      \
  do {                                                                        \
    _Pragma("unroll") for (int f = 0; f < 2; ++f) {                           \
      const int rb = (co) + (wc * 64 + (nh) * 32 + f * 16 + lm) * 64;         \
      bfx[f][0] = *(const short8*)&Bb[rb + cK0];                              \
      bfx[f][1] = *(const short8*)&Bb[rb + cK1];                              \
    }                                                                         \
  } while (0)
#define MMA(mh, nh, bfx)                                                      \
  do {                                                                        \
    __builtin_amdgcn_s_setprio(1);                                            \
    _Pragma("unroll") for (int ks = 0; ks < 2; ++ks)                          \
    _Pragma("unroll") for (int f = 0; f < 4; ++f)                             \
    _Pragma("unroll") for (int f2 = 0; f2 < 2; ++f2)                          \
      acc[(mh) * 4 + f][(nh) * 2 + f2] =                                      \
          __builtin_amdgcn_mfma_f32_16x16x32_bf16(                            \
              af[f][ks], bfx[f2][ks], acc[(mh) * 4 + f][(nh) * 2 + f2],       \
              0, 0, 0);                                                       \
    __builtin_amdgcn_s_setprio(0);                                            \
  } while (0)

  // Prologue: stage tile 0 in FIFO order A0,B0,B1,A1 (2 loads each).
  STG(Ag, Asw, 0, 0);
  STG(Bg, Bsw, 0, 0);
  STG(Bg, Bsw, 1, 0);
  STG(Ag, Asw, 1, 0);
  asm volatile("s_waitcnt vmcnt(4)" ::: "memory");  // A0,B0 landed
  BAR;

  for (int t = 0; t < 15; ++t) {
    const int co = (t & 1) << 14;        // compute buffer (ushort offset)
    const int so = ((t + 1) & 1) << 14;  // stage buffer
    const int ko = (t + 1) * 64;
    // P0: quadrant (0,0); stage A0,B0 of t+1
    LDA(0, co);
    LDB(bf0, 0, co);
    STG(Ag, Asw + so, 0, ko);
    STG(Bg, Bsw + so, 0, ko);
    BAR;
    MMA(0, 0, bf0);
    asm volatile("s_waitcnt vmcnt(6)" ::: "memory");  // B1(t) landed
    BAR;
    // P1: quadrant (0,1); stage B1 of t+1
    LDB(bf1, 1, co);
    STG(Bg, Bsw + so, 1, ko);
    BAR;
    MMA(0, 1, bf1);
    asm volatile("s_waitcnt vmcnt(6)" ::: "memory");  // A1(t) landed
    BAR;
    // P2: quadrant (1,0); stage A1 of t+1
    LDA(1, co);
    STG(Ag, Asw + so, 1, ko);
    BAR;
    MMA(1, 0, bf0);
    BAR;
    // P3: quadrant (1,1); regs only
    MMA(1, 1, bf1);
    asm volatile("s_waitcnt vmcnt(4)" ::: "memory");  // A0,B0(t+1) landed
    BAR;
  }
  {  // final tile t = 15, exact drain
    const int co = 1 << 14;
    LDA(0, co);
    LDB(bf0, 0, co);
    BAR;
    MMA(0, 0, bf0);
    asm volatile("s_waitcnt vmcnt(2)" ::: "memory");  // B1(15) landed
    BAR;
    LDB(bf1, 1, co);
    BAR;
    MMA(0, 1, bf1);
    asm volatile("s_waitcnt vmcnt(0)" ::: "memory");  // A1(15) landed
    BAR;
    LDA(1, co);
    BAR;
    MMA(1, 0, bf0);
    BAR;
    MMA(1, 1, bf1);
    BAR;  // publish: all LDS reads done before epilogue reuses smem
  }
#undef MMA
#undef LDB
#undef LDA
#undef STG
#undef BAR
#undef FENCE
}

// ---------------------------------------------------------------------------
// NEW: QKV projection, 256x256 tiles. grid 384 (XCD-swizzled), block 512.
// Wave tile 128x64 = one head's columns for 128 (b,s)-rows.
// ---------------------------------------------------------------------------
__global__ __launch_bounds__(512, 2) void qkv256_kernel(
    const ushort_t* __restrict__ Abf, const ushort_t* __restrict__ Wt,
    const float* __restrict__ Bias, ushort_t* __restrict__ Qh,
    ushort_t* __restrict__ Kh, ushort_t* __restrict__ Vh) {
  __shared__ __align__(16) ushort_t smem[65536];  // 128 KiB
  const int bid = blockIdx.x;
  const int sw = (bid & 7) * 48 + (bid >> 3);  // XCD-bijective (384 % 8 == 0)
  const int z = sw >> 7;                       // 0..2
  const int tt = sw & 127;                     // 32 m-tiles x 4 n-tiles
  const int m0 = (tt >> 2) * 256, n0 = (tt & 3) * 256;
  const ushort_t* A = Abf + (size_t)z * (8192 * (size_t)DMODEL);
  const ushort_t* B = Wt + (size_t)z * (DMODEL * (size_t)DMODEL);

  floatx4 acc[8][4] = {};
  gemm256_core(A, B, m0, n0, smem, acc);

  const int tid = threadIdx.x;
  const int w = tid >> 6, l = tid & 63;
  const int wr = w >> 2, wc = w & 3;
  const int lm = l & 15, lg = l >> 4;
  const int lr8 = l >> 3, lc8 = l & 7;
  ushort_t* dst = z == 0 ? Qh : z == 1 ? Kh : Vh;

  ushort_t* ep = smem + w * 8192;  // per-wave 16 KiB scratch
  const int n_base = n0 + wc * 64;
#pragma unroll
  for (int nf = 0; nf < 4; ++nf) {
    const int c = nf * 16 + lm;
    const float bval = Bias[z * DMODEL + n_base + c];
#pragma unroll
    for (int mf = 0; mf < 8; ++mf)
#pragma unroll
      for (int r = 0; r < 4; ++r) {
        const int rowt = mf * 16 + lg * 4 + r;
        ep[rowt * 64 + ((((c >> 3) ^ (rowt & 7)) << 3) | (c & 7))] =
            f2b(acc[mf][nf][r] + bval);
      }
  }
  const int mg = m0 + wr * 128;
  const int b_ = mg >> 11, s_base = mg & (S_LEN - 1);
  const int h_ = n_base >> 6;
  ushort_t* dstb = dst + (((size_t)(b_ * NHEAD + h_) * S_LEN + s_base) << 6);
#pragma unroll
  for (int i = 0; i < 16; ++i) {
    const int row = lr8 + 8 * i;
    const short8 v2 = *(const short8*)&ep[row * 64 + ((lc8 ^ lr8) << 3)];
    *(short8*)(dstb + ((size_t)row << 6) + lc8 * 8) = v2;
  }
}

// ---------------------------------------------------------------------------
// QKV projection GEMM (bf16 MFMA) + bias -> bf16 [B,H,S,64]  [FALLBACK PATH]
// grid (64, 8, 3), block 256. LDS tiles xor-swizzled (16B block ^ (row&7)).
// ---------------------------------------------------------------------------
__global__ __launch_bounds__(256) void qkv_kernel(
    const void* __restrict__ qin, const void* __restrict__ kin,
    const void* __restrict__ vin, const ushort_t* __restrict__ Wt,
    const float* __restrict__ Bias, const int* __restrict__ flag,
    ushort_t* __restrict__ Qh, ushort_t* __restrict__ Kh,
    ushort_t* __restrict__ Vh) {
  const int z = blockIdx.z;
  const void* A = z == 0 ? qin : z == 1 ? kin : vin;
  const ushort_t* W = Wt + (size_t)z * (DMODEL * (size_t)DMODEL);
  ushort_t* dst = z == 0 ? Qh : z == 1 ? Kh : Vh;
  const int isbf = *flag;

  __shared__ __align__(16) ushort_t smem[2 * 128 * 64];
  ushort_t* As = smem;
  ushort_t* Bs = smem + 128 * 64;

  const int tid = threadIdx.x;
  const int w = tid >> 6, l = tid & 63;
  const int m0 = blockIdx.x * 128, n0 = blockIdx.y * 128;

  floatx4 acc[4][4] = {};

  const int lr8 = l >> 3, lc8 = l & 7;
  const int gblk = lc8 ^ lr8;
  const ushort_t* Agb =
      (const ushort_t*)A + (size_t)(m0 + w * 32 + lr8) * DMODEL + gblk * 8;
  const float* Agf =
      (const float*)A + (size_t)(m0 + w * 32 + (l >> 4)) * DMODEL + (l & 15) * 4;
  const ushort_t* Bg = W + (size_t)(n0 + w * 32 + lr8) * DMODEL + gblk * 8;
  ushort_t* Asw = As + (w * 32) * 64;
  ushort_t* Bsw = Bs + (w * 32) * 64;

  const int wm = (w >> 1) * 64, wn = (w & 1) * 64;
  const int lm = l & 15, lg = l >> 4;
  const int swz = lm & 7;
  const int cA0 = ((0 + lg) ^ swz) * 8;
  const int cA1 = ((4 + lg) ^ swz) * 8;

  for (int kt = 0; kt < 16; ++kt) {
    const int ko = kt * 64;
    if (isbf) {
#pragma unroll
      for (int i = 0; i < 4; ++i)
        gld16(Agb + (size_t)(i * 8) * DMODEL + ko, Asw + (i * 8) * 64);
    } else {
#pragma unroll
      for (int i = 0; i < 8; ++i) {
        const floatx4 x = *(const floatx4*)(Agf + (size_t)(i * 4) * DMODEL + ko);
        ushort4v h;
        h[0] = f2b(x.x); h[1] = f2b(x.y); h[2] = f2b(x.z); h[3] = f2b(x.w);
        const int row = i * 4 + (l >> 4);
        const int blk = ((l & 15) >> 1) ^ (row & 7);
        *(ushort4v*)&Asw[row * 64 + blk * 8 + (l & 1) * 4] = h;
      }
    }
#pragma unroll
    for (int i = 0; i < 4; ++i)
      gld16(Bg + (size_t)(i * 8) * DMODEL + ko, Bsw + (i * 8) * 64);
    __syncthreads();
#pragma unroll
    for (int kk = 0; kk < 64; kk += 32) {
      const int ck = kk ? cA1 : cA0;
      short8 af[4], bf[4];
#pragma unroll
      for (int t = 0; t < 4; ++t)
        af[t] = *(const short8*)&As[(wm + t * 16 + lm) * 64 + ck];
#pragma unroll
      for (int t = 0; t < 4; ++t)
        bf[t] = *(const short8*)&Bs[(wn + t * 16 + lm) * 64 + ck];
#pragma unroll
      for (int mt = 0; mt < 4; ++mt)
#pragma unroll
        for (int nt = 0; nt < 4; ++nt)
          acc[mt][nt] = __builtin_amdgcn_mfma_f32_16x16x32_bf16(
              af[mt], bf[nt], acc[mt][nt], 0, 0, 0);
    }
    __syncthreads();
  }

  ushort_t* ep = smem + w * 4096;
#pragma unroll
  for (int nt = 0; nt < 4; ++nt) {
    const int c = nt * 16 + lm;
    const float bval = Bias[z * DMODEL + n0 + wn + c];
#pragma unroll
    for (int mt = 0; mt < 4; ++mt)
#pragma unroll
      for (int r = 0; r < 4; ++r) {
        const int row_t = mt * 16 + lg * 4 + r;
        ep[row_t * 64 + ((((c >> 3) ^ (row_t & 7)) << 3) | (c & 7))] =
            f2b(acc[mt][nt][r] + bval);
      }
  }
  const int mg = m0 + wm;
  const int b_ = mg >> 11, s_base = mg & (S_LEN - 1);
  const int h_ = (n0 + wn) >> 6;
  ushort_t* dstb = dst + (((size_t)(b_ * NHEAD + h_) * S_LEN + s_base) << 6);
#pragma unroll
  for (int i = 0; i < 8; ++i) {
    const int row = lr8 + 8 * i;
    const short8 v = *(const short8*)&ep[row * 64 + ((lc8 ^ lr8) << 3)];
    *(short8*)(dstb + (size_t)row * 64 + lc8 * 8) = v;
  }
}

// ---------------------------------------------------------------------------
// RoPE in-place over Qh and Kh (contiguous)
// ---------------------------------------------------------------------------
__global__ __launch_bounds__(256) void rope_kernel(ushort_t* __restrict__ QK) {
  const size_t p = (size_t)blockIdx.x * 256 + threadIdx.x;
  const int d2 = (int)(p & 31) * 2;
  const int s = (int)(p >> 5) & (S_LEN - 1);
  const int h = (int)(p >> 16) & (NHEAD - 1);
  const int n = h * HDIM + d2;
  const float freq = exp2f((float)n * (-13.287712379549449f / 1024.0f));
  float sn, cs;
  __sincosf((float)s * freq, &sn, &cs);
  ushort2v v = *(ushort2v*)(QK + 2 * p);
  const float re = b2f(v[0]), im = b2f(v[1]);
  ushort2v o;
  o[0] = f2b(re * cs - im * sn);
  o[1] = f2b(re * sn + im * cs);
  *(ushort2v*)(QK + 2 * p) = o;
}

// ---------------------------------------------------------------------------
// V transpose per (b,h): [s][d] -> [d][s]
// grid (64, 2, 64), block 256
// ---------------------------------------------------------------------------
__global__ __launch_bounds__(256) void vtrans_kernel(
    const ushort_t* __restrict__ V, ushort_t* __restrict__ Vt) {
  __shared__ ushort_t t[32][34];
  const int bh = blockIdx.z;
  const int s0 = blockIdx.x * 32, d0 = blockIdx.y * 32;
  const ushort_t* src = V + (size_t)bh * S_LEN * HDIM;
  ushort_t* dst = Vt + (size_t)bh * S_LEN * HDIM;
  const int tx = threadIdx.x & 31, ty = threadIdx.x >> 5;
#pragma unroll
  for (int i = 0; i < 4; ++i)
    t[ty + 8 * i][tx] = src[(size_t)(s0 + ty + 8 * i) * HDIM + d0 + tx];
  __syncthreads();
#pragma unroll
  for (int i = 0; i < 4; ++i)
    dst[(size_t)(d0 + ty + 8 * i) * S_LEN + s0 + tx] = t[tx][ty + 8 * i];
}

// ---------------------------------------------------------------------------
// Flash attention, bf16 MFMA, no-max softmax (energies bounded << 88;
// masked -> -50 so an all-masked row degrades to the exact uniform average).
// Row-sum l from an all-ones B-block in the PV MFMA. K/V LDS xor-swizzled.
// grid (16, 64) with XCD-locality swizzle, block 256 (4 waves).
// ---------------------------------------------------------------------------
__global__ __launch_bounds__(256) void attn_kernel(
    const ushort_t* __restrict__ Qh, const ushort_t* __restrict__ Kh,
    const ushort_t* __restrict__ Vt, const int* __restrict__ mask,
    ushort_t* __restrict__ Xa) {
  const int nlin = blockIdx.y * 16 + blockIdx.x;
  const int bh = ((nlin & 7) << 3) | ((nlin >> 3) & 7);
  const int q0 = (nlin >> 6) * 128;
  const int b = bh >> 4, h = bh & 15;
  const int tid = threadIdx.x;
  const int w = tid >> 6, lane = tid & 63;
  const int lm = lane & 15, lg = lane >> 4;

  __shared__ __align__(16) ushort_t Ks[64 * 64];
  __shared__ __align__(16) ushort_t Vs[64 * 64];
  __shared__ __align__(16) ushort_t Ps[4][32 * 72];

  const ushort_t* Qb = Qh + ((size_t)bh * S_LEN + q0 + w * 32) * HDIM;
  const ushort_t* Kb = Kh + (size_t)bh * S_LEN * HDIM;
  const ushort_t* Vb = Vt + (size_t)bh * S_LEN * HDIM;
  const int* mb = mask + b * S_LEN;

  short8 qf[2][2];
#pragma unroll
  for (int mb_ = 0; mb_ < 2; ++mb_)
#pragma unroll
    for (int ks = 0; ks < 2; ++ks)
      qf[mb_][ks] = *(const short8*)(Qb + (size_t)(mb_ * 16 + lm) * HDIM +
                                     ks * 32 + lg * 8);

  const int lr8 = lane >> 3, lc8 = lane & 7;
  const int gblk = lc8 ^ lr8;
  const ushort_t* Kg = Kb + (size_t)(w * 16 + lr8) * HDIM + gblk * 8;
  const ushort_t* Vg = Vb + (size_t)(w * 16 + lr8) * S_LEN + gblk * 8;
  ushort_t* KsW = Ks + (w * 16) * 64;
  ushort_t* VsW = Vs + (w * 16) * 64;

  const int swz = lm & 7;
  const int cK0 = ((0 + lg) ^ swz) * 8;
  const int cK1 = ((4 + lg) ^ swz) * 8;

  floatx4 Oacc[2][5] = {};

  const short8 ones = {0x3F80, 0x3F80, 0x3F80, 0x3F80,
                       0x3F80, 0x3F80, 0x3F80, 0x3F80};

  for (int j0 = 0; j0 < S_LEN; j0 += 64) {
    __syncthreads();
    gld16(Kg + (size_t)j0 * HDIM, KsW);
    gld16(Kg + (size_t)(j0 + 8) * HDIM, KsW + 8 * 64);
    gld16(Vg + j0, VsW);
    gld16(Vg + (size_t)8 * S_LEN + j0, VsW + 8 * 64);
    int mj[4];
#pragma unroll
    for (int nb = 0; nb < 4; ++nb) mj[nb] = mb[j0 + nb * 16 + lm];
    __syncthreads();

    floatx4 Sacc[2][4] = {};
#pragma unroll
    for (int ks = 0; ks < 2; ++ks) {
      const int ck = ks ? cK1 : cK0;
      short8 kf[4];
#pragma unroll
      for (int nb = 0; nb < 4; ++nb)
        kf[nb] = *(const short8*)&Ks[(nb * 16 + lm) * 64 + ck];
#pragma unroll
      for (int mb_ = 0; mb_ < 2; ++mb_)
#pragma unroll
        for (int nb = 0; nb < 4; ++nb)
          Sacc[mb_][nb] = __builtin_amdgcn_mfma_f32_16x16x32_bf16(
              qf[mb_][ks], kf[nb], Sacc[mb_][nb], 0, 0, 0);
    }

#pragma unroll
    for (int mb_ = 0; mb_ < 2; ++mb_)
#pragma unroll
      for (int nb = 0; nb < 4; ++nb)
#pragma unroll
        for (int r = 0; r < 4; ++r) {
          const float sv = Sacc[mb_][nb][r] * 0.125f;
          const float p = __expf(mj[nb] ? sv : -50.0f);
          Ps[w][(mb_ * 16 + lg * 4 + r) * 72 + nb * 16 + lm] = f2b(p);
        }

#pragma unroll
    for (int ks = 0; ks < 2; ++ks) {
      const int ck = ks ? cK1 : cK0;
      short8 pf[2], vf[4];
#pragma unroll
      for (int mb_ = 0; mb_ < 2; ++mb_)
        pf[mb_] =
            *(const short8*)&Ps[w][(mb_ * 16 + lm) * 72 + ks * 32 + lg * 8];
#pragma unroll
      for (int nb = 0; nb < 4; ++nb)
        vf[nb] = *(const short8*)&Vs[(nb * 16 + lm) * 64 + ck];
#pragma unroll
      for (int mb_ = 0; mb_ < 2; ++mb_) {
#pragma unroll
        for (int nb = 0; nb < 4; ++nb)
          Oacc[mb_][nb] = __builtin_amdgcn_mfma_f32_16x16x32_bf16(
              pf[mb_], vf[nb], Oacc[mb_][nb], 0, 0, 0);
        Oacc[mb_][4] = __builtin_amdgcn_mfma_f32_16x16x32_bf16(
            pf[mb_], ones, Oacc[mb_][4], 0, 0, 0);
      }
    }
  }

#pragma unroll
  for (int mb_ = 0; mb_ < 2; ++mb_)
#pragma unroll
    for (int r = 0; r < 4; ++r) {
      const float inv = 1.0f / Oacc[mb_][4][r];
      const int q = q0 + w * 32 + mb_ * 16 + lg * 4 + r;
      ushort_t* orow = Xa + (size_t)(b * S_LEN + q) * DMODEL + h * HDIM;
#pragma unroll
      for (int nb = 0; nb < 4; ++nb)
        orow[nb * 16 + lm] = f2b(Oacc[mb_][nb][r] * inv);
    }
}

// ---------------------------------------------------------------------------
// Output projection: bf16 GEMM (swizzled LDS); bf16 out via LDS-repacked
// coalesced stores, fp32 out via scalar stores. grid (64, 8)
// ---------------------------------------------------------------------------
__global__ __launch_bounds__(256) void oproj_kernel(
    const ushort_t* __restrict__ X, const ushort_t* __restrict__ Wt,
    const float* __restrict__ BiasO, const int* __restrict__ flag,
    void* __restrict__ out) {
  const int isbf = *flag;
  __shared__ __align__(16) ushort_t smem[2 * 128 * 64];
  ushort_t* As = smem;
  ushort_t* Bs = smem + 128 * 64;
  const int tid = threadIdx.x;
  const int w = tid >> 6, l = tid & 63;
  const int m0 = blockIdx.x * 128, n0 = blockIdx.y * 128;

  floatx4 acc[4][4] = {};

  const int lr8 = l >> 3, lc8 = l & 7;
  const int gblk = lc8 ^ lr8;
  const ushort_t* Ag =
      X + (size_t)(m0 + w * 32 + lr8) * DMODEL + gblk * 8;
  const ushort_t* Bg =
      Wt + (size_t)(n0 + w * 32 + lr8) * DMODEL + gblk * 8;
  ushort_t* Asw = As + (w * 32) * 64;
  ushort_t* Bsw = Bs + (w * 32) * 64;

  const int wm = (w >> 1) * 64, wn = (w & 1) * 64;
  const int lm = l & 15, lg = l >> 4;
  const int swz = lm & 7;
  const int cA0 = ((0 + lg) ^ swz) * 8;
  const int cA1 = ((4 + lg) ^ swz) * 8;

  for (int kt = 0; kt < 16; ++kt) {
    const int ko = kt * 64;
#pragma unroll
    for (int i = 0; i < 4; ++i) {
      gld16(Ag + (size_t)(i * 8) * DMODEL + ko, Asw + (i * 8) * 64);
      gld16(Bg + (size_t)(i * 8) * DMODEL + ko, Bsw + (i * 8) * 64);
    }
    __syncthreads();
#pragma unroll
    for (int kk = 0; kk < 64; kk += 32) {
      const int ck = kk ? cA1 : cA0;
      short8 af[4], bf[4];
#pragma unroll
      for (int t = 0; t < 4; ++t)
        af[t] = *(const short8*)&As[(wm + t * 16 + lm) * 64 + ck];
#pragma unroll
      for (int t = 0; t < 4; ++t)
        bf[t] = *(const short8*)&Bs[(wn + t * 16 + lm) * 64 + ck];
#pragma unroll
      for (int mt = 0; mt < 4; ++mt)
#pragma unroll
        for (int nt = 0; nt < 4; ++nt)
          acc[mt][nt] = __builtin_amdgcn_mfma_f32_16x16x32_bf16(
              af[mt], bf[nt], acc[mt][nt], 0, 0, 0);
    }
    __syncthreads();
  }

  if (isbf) {
    ushort_t* ep = smem + w * 4096;
#pragma unroll
    for (int nt = 0; nt < 4; ++nt) {
      const int c = nt * 16 + lm;
      const float bval = BiasO[n0 + wn + c];
#pragma unroll
      for (int mt = 0; mt < 4; ++mt)
#pragma unroll
        for (int r = 0; r < 4; ++r) {
          const int row_t = mt * 16 + lg * 4 + r;
          ep[row_t * 64 + ((((c >> 3) ^ (row_t & 7)) << 3) | (c & 7))] =
              f2b(acc[mt][nt][r] + bval);
        }
    }
    ushort_t* outb = (ushort_t*)out + (size_t)(m0 + wm) * DMODEL + n0 + wn;
#pragma unroll
    for (int i = 0; i < 8; ++i) {
      const int row = lr8 + 8 * i;
      const short8 v = *(const short8*)&ep[row * 64 + ((lc8 ^ lr8) << 3)];
      *(short8*)(outb + (size_t)row * DMODEL + lc8 * 8) = v;
    }
  } else {
    const int lr = lg * 4;
#pragma unroll
    for (int nt = 0; nt < 4; ++nt) {
      const int n_g = n0 + wn + nt * 16 + lm;
      const float bval = BiasO[n_g];
#pragma unroll
      for (int mt = 0; mt < 4; ++mt)
#pragma unroll
        for (int r = 0; r < 4; ++r) {
          const int m_g = m0 + wm + mt * 16 + lr + r;
          ((float*)out)[(size_t)m_g * DMODEL + n_g] = acc[mt][nt][r] + bval;
        }
    }
  }
}

// ---------------------------------------------------------------------------
extern "C" void kernel_launch(void* const* d_in, const int* in_sizes, int n_in,
                              void* d_out, int out_size, void* d_ws,
                              size_t ws_size, hipStream_t stream) {
  char* ws = (char*)d_ws;
  const size_t MB = 1024 * 1024;
  int* flag = (int*)ws;                          // 4 B
  float* Bias = (float*)(ws + 4096);             // 16 KB, [q|k|v|o]
  ushort_t* Wt = (ushort_t*)(ws + 1 * MB);       // 8 MB bf16 (q,k,v,o) n-major
  ushort_t* Qh = (ushort_t*)(ws + 16 * MB);      // 16 MB bf16 [B,H,S,64]
  ushort_t* Kh = (ushort_t*)(ws + 32 * MB);      // 16 MB (contiguous after Qh)
  ushort_t* Vh = (ushort_t*)(ws + 48 * MB);      // 16 MB (dead after vtrans)
  ushort_t* Vt = (ushort_t*)(ws + 64 * MB);      // 16 MB bf16 [B,H,64,S]
  ushort_t* Abf = (ushort_t*)(ws + 80 * MB);     // 48 MB bf16 A (q,k,v)
  ushort_t* Xa = Vh;                             // reuse Vh region [B*S, D]

  const int use256 = ws_size >= (size_t)128 * MB;

  detect_kernel<<<1, 256, 0, stream>>>((const unsigned*)d_in[0], flag);
  bias_kernel<<<16, 256, 0, stream>>>(d_in[4], d_in[6], d_in[8], d_in[10],
                                      flag, Bias);
  wtrans_kernel<<<dim3(32, 32, 4), 256, 0, stream>>>(d_in[3], d_in[5], d_in[7],
                                                     d_in[9], flag, Wt);
  if (use256) {
    convert_kernel<<<dim3(4096, 3), 256, 0, stream>>>(d_in[0], d_in[1],
                                                      d_in[2], flag, Abf);
    qkv256_kernel<<<384, 512, 0, stream>>>(Abf, Wt, Bias, Qh, Kh, Vh);
  } else {
    qkv_kernel<<<dim3(64, 8, 3), 256, 0, stream>>>(d_in[0], d_in[1], d_in[2],
                                                   Wt, Bias, flag, Qh, Kh, Vh);
  }
  rope_kernel<<<32768, 256, 0, stream>>>(Qh);  // covers Qh+Kh (contiguous)
  vtrans_kernel<<<dim3(64, 2, 64), 256, 0, stream>>>(Vh, Vt);
  attn_kernel<<<dim3(16, 64), 256, 0, stream>>>(Qh, Kh, Vt,
                                                (const int*)d_in[11], Xa);
  oproj_kernel<<<dim3(64, 8), 256, 0, stream>>>(
      Xa, Wt + (size_t)3 * DMODEL * DMODEL, Bias + 3 * DMODEL, flag, d_out);
}

// Round 4
// 392.453 us; speedup vs baseline: 1.1228x; 1.0261x over previous
//
#include <hip/hip_runtime.h>
#include <hip/hip_bf16.h>
#include <math.h>

#define S_LEN 2048
#define DMODEL 1024
#define NHEAD 16
#define HDIM 64

typedef unsigned short ushort_t;
typedef __attribute__((ext_vector_type(8))) short short8;
typedef __attribute__((ext_vector_type(4))) float floatx4;
typedef __attribute__((ext_vector_type(4))) unsigned short ushort4v;
typedef __attribute__((ext_vector_type(2))) unsigned short ushort2v;

typedef __attribute__((address_space(3))) unsigned int lds_uint;
typedef const __attribute__((address_space(1))) unsigned int gbl_uint;

__device__ __forceinline__ float b2f(ushort_t u) {
  return __uint_as_float(((unsigned)u) << 16);
}
__device__ __forceinline__ ushort_t f2b(float x) {
  unsigned u = __float_as_uint(x);
  return (ushort_t)((u + 0x7fffu + ((u >> 16) & 1u)) >> 16);
}
__device__ __forceinline__ void gld16(const void* g, void* l) {
  __builtin_amdgcn_global_load_lds((gbl_uint*)g, (lds_uint*)l, 16, 0, 0);
}
__device__ __forceinline__ float exp2_fast(float x) {
#if __has_builtin(__builtin_amdgcn_exp2f)
  return __builtin_amdgcn_exp2f(x);
#else
  return exp2f(x);
#endif
}
// HW bf16 convert with HIP-defined RNE semantics
__device__ __forceinline__ ushort_t f2b_hw(float x) {
  __hip_bfloat16 h = __float2bfloat16(x);
  return *(ushort_t*)&h;
}

// ---------------------------------------------------------------------------
// Dtype detection: 1 = bf16 inputs, 0 = fp32 inputs.
// ---------------------------------------------------------------------------
__global__ __launch_bounds__(256) void detect_kernel(
    const unsigned* __restrict__ q, int* __restrict__ flag) {
  __shared__ int cnt[256];
  int c = 0;
#pragma unroll
  for (int i = 0; i < 16; ++i) {
    const unsigned w = q[threadIdx.x * 16 + i];
    const unsigned e = (w >> 7) & 0xFFu;
    c += (e >= 112u && e <= 135u) ? 1 : 0;
  }
  cnt[threadIdx.x] = c;
  __syncthreads();
  if (threadIdx.x == 0) {
    int t = 0;
    for (int i = 0; i < 256; ++i) t += cnt[i];
    *flag = (t > 2048) ? 1 : 0;
  }
}

// ---------------------------------------------------------------------------
// Biases -> fp32 ws buffer [4][1024] in order q,k,v,o
// ---------------------------------------------------------------------------
__global__ __launch_bounds__(256) void bias_kernel(
    const void* __restrict__ bq, const void* __restrict__ bk,
    const void* __restrict__ bv, const void* __restrict__ bo,
    const int* __restrict__ flag, float* __restrict__ out) {
  const int i = blockIdx.x * 256 + threadIdx.x;
  const int z = i >> 10;
  const void* src = z == 0 ? bq : z == 1 ? bk : z == 2 ? bv : bo;
  const int j = i & 1023;
  const float v = (*flag) ? b2f(((const ushort_t*)src)[j])
                          : ((const float*)src)[j];
  out[i] = v;
}

// ---------------------------------------------------------------------------
// Weight transpose (either dtype) -> bf16 Wt[n][k], 4 weights
// ---------------------------------------------------------------------------
__global__ __launch_bounds__(256) void wtrans_kernel(
    const void* __restrict__ Wq, const void* __restrict__ Wk,
    const void* __restrict__ Wv, const void* __restrict__ Wo,
    const int* __restrict__ flag, ushort_t* __restrict__ Wt) {
  __shared__ float t[32][33];
  const void* src = blockIdx.z == 0 ? Wq : blockIdx.z == 1 ? Wk
                    : blockIdx.z == 2 ? Wv : Wo;
  ushort_t* dst = Wt + (size_t)blockIdx.z * (DMODEL * (size_t)DMODEL);
  const int isbf = *flag;
  const int tx = threadIdx.x & 31, ty = threadIdx.x >> 5;
  const int bx = blockIdx.x * 32, by = blockIdx.y * 32;
#pragma unroll
  for (int i = 0; i < 4; ++i) {
    const size_t idx = (size_t)(by + ty + 8 * i) * DMODEL + bx + tx;
    t[ty + 8 * i][tx] = isbf ? b2f(((const ushort_t*)src)[idx])
                             : ((const float*)src)[idx];
  }
  __syncthreads();
#pragma unroll
  for (int i = 0; i < 4; ++i)
    dst[(size_t)(bx + ty + 8 * i) * DMODEL + by + tx] = f2b(t[tx][ty + 8 * i]);
}

// ---------------------------------------------------------------------------
// input activation convert (fp32 -> bf16, or bf16 copy) -> Abf[z][8192][1024]
// grid (4096, 3), block 256; one short8 (8 elems) per thread.
// ---------------------------------------------------------------------------
__global__ __launch_bounds__(256) void convert_kernel(
    const void* __restrict__ q, const void* __restrict__ k,
    const void* __restrict__ v, const int* __restrict__ flag,
    ushort_t* __restrict__ Abf) {
  const int z = blockIdx.y;
  const void* src = z == 0 ? q : z == 1 ? k : v;
  ushort_t* dst = Abf + (size_t)z * (8192 * (size_t)DMODEL);
  const size_t i = (size_t)blockIdx.x * 256 + threadIdx.x;  // vec8 index
  short8 o;
  if (*flag) {
    o = ((const short8*)src)[i];
  } else {
    const floatx4 a = ((const floatx4*)src)[2 * i];
    const floatx4 b = ((const floatx4*)src)[2 * i + 1];
    o[0] = (short)f2b(a.x); o[1] = (short)f2b(a.y);
    o[2] = (short)f2b(a.z); o[3] = (short)f2b(a.w);
    o[4] = (short)f2b(b.x); o[5] = (short)f2b(b.y);
    o[6] = (short)f2b(b.z); o[7] = (short)f2b(b.w);
  }
  ((short8*)dst)[i] = o;
}

// ---------------------------------------------------------------------------
// 256x256 / BK=64 / 8-wave GEMM core with 4-phase counted-vmcnt schedule.
// ---------------------------------------------------------------------------
__device__ __forceinline__ void gemm256_core(
    const ushort_t* __restrict__ A, const ushort_t* __restrict__ Bm,
    const int m0, const int n0, ushort_t* smem, floatx4 acc[8][4]) {
  const int tid = threadIdx.x;
  const int w = tid >> 6, l = tid & 63;
  const int wr = w >> 2, wc = w & 3;
  const int lm = l & 15, lg = l >> 4;
  const int lr8 = l >> 3, lc8 = l & 7;
  const int gblk = lc8 ^ lr8;

  ushort_t* Ab = smem;            // [2][256][64]
  ushort_t* Bb = smem + 32768;    // [2][256][64]

  const ushort_t* Ag = A + (size_t)(m0 + w * 16 + lr8) * DMODEL + gblk * 8;
  const ushort_t* Bg = Bm + (size_t)(n0 + w * 16 + lr8) * DMODEL + gblk * 8;
  ushort_t* Asw = Ab + (w * 16) * 64;  // wave-uniform LDS stage base
  ushort_t* Bsw = Bb + (w * 16) * 64;

  const int swz = lm & 7;
  const int cK0 = ((0 + lg) ^ swz) * 8;
  const int cK1 = ((4 + lg) ^ swz) * 8;

  short8 af[4][2], bf0[2][2], bf1[2][2];

#define FENCE asm volatile("" ::: "memory")
#define BAR                        \
  do {                             \
    FENCE;                         \
    __builtin_amdgcn_s_barrier();  \
    FENCE;                         \
  } while (0)
#define STG(gp, lp, h, ko)                                                    \
  do {                                                                        \
    gld16((gp) + (size_t)((h) * 128) * DMODEL + (ko),                         \
          (lp) + ((h) * 128) * 64);                                           \
    gld16((gp) + (size_t)((h) * 128 + 8) * DMODEL + (ko),                     \
          (lp) + ((h) * 128 + 8) * 64);                                       \
  } while (0)
#define LDA(mh, co)                                                           \
  do {                                                                        \
    _Pragma("unroll") for (int f = 0; f < 4; ++f) {                           \
      const int ra = (co) + (wr * 128 + (mh) * 64 + f * 16 + lm) * 64;        \
      af[f][0] = *(const short8*)&Ab[ra + cK0];                               \
      af[f][1] = *(const short8*)&Ab[ra + cK1];                               \
    }                                                                         \
  } while (0)
#define LDB(bfx, nh, co)                                                      \
  do {                                                                        \
    _Pragma("unroll") for (int f = 0; f < 2; ++f) {                           \
      const int rb = (co) + (wc * 64 + (nh) * 32 + f * 16 + lm) * 64;         \
      bfx[f][0] = *(const short8*)&Bb[rb + cK0];                              \
      bfx[f][1] = *(const short8*)&Bb[rb + cK1];                              \
    }                                                                         \
  } while (0)
#define MMA(mh, nh, bfx)                                                      \
  do {                                                                        \
    __builtin_amdgcn_s_setprio(1);                                            \
    _Pragma("unroll") for (int ks = 0; ks < 2; ++ks)                          \
    _Pragma("unroll") for (int f = 0; f < 4; ++f)                             \
    _Pragma("unroll") for (int f2 = 0; f2 < 2; ++f2)                          \
      acc[(mh) * 4 + f][(nh) * 2 + f2] =                                      \
          __builtin_amdgcn_mfma_f32_16x16x32_bf16(                            \
              af[f][ks], bfx[f2][ks], acc[(mh) * 4 + f][(nh) * 2 + f2],       \
              0, 0, 0);                                                       \
    __builtin_amdgcn_s_setprio(0);                                            \
  } while (0)

  // Prologue: stage tile 0 in FIFO order A0,B0,B1,A1 (2 loads each).
  STG(Ag, Asw, 0, 0);
  STG(Bg, Bsw, 0, 0);
  STG(Bg, Bsw, 1, 0);
  STG(Ag, Asw, 1, 0);
  asm volatile("s_waitcnt vmcnt(4)" ::: "memory");  // A0,B0 landed
  BAR;

  for (int t = 0; t < 15; ++t) {
    const int co = (t & 1) << 14;        // compute buffer (ushort offset)
    const int so = ((t + 1) & 1) << 14;  // stage buffer
    const int ko = (t + 1) * 64;
    // P0: quadrant (0,0); stage A0,B0 of t+1
    LDA(0, co);
    LDB(bf0, 0, co);
    STG(Ag, Asw + so, 0, ko);
    STG(Bg, Bsw + so, 0, ko);
    BAR;
    MMA(0, 0, bf0);
    asm volatile("s_waitcnt vmcnt(6)" ::: "memory");  // B1(t) landed
    BAR;
    // P1: quadrant (0,1); stage B1 of t+1
    LDB(bf1, 1, co);
    STG(Bg, Bsw + so, 1, ko);
    BAR;
    MMA(0, 1, bf1);
    asm volatile("s_waitcnt vmcnt(6)" ::: "memory");  // A1(t) landed
    BAR;
    // P2: quadrant (1,0); stage A1 of t+1
    LDA(1, co);
    STG(Ag, Asw + so, 1, ko);
    BAR;
    MMA(1, 0, bf0);
    BAR;
    // P3: quadrant (1,1); regs only
    MMA(1, 1, bf1);
    asm volatile("s_waitcnt vmcnt(4)" ::: "memory");  // A0,B0(t+1) landed
    BAR;
  }
  {  // final tile t = 15, exact drain
    const int co = 1 << 14;
    LDA(0, co);
    LDB(bf0, 0, co);
    BAR;
    MMA(0, 0, bf0);
    asm volatile("s_waitcnt vmcnt(2)" ::: "memory");  // B1(15) landed
    BAR;
    LDB(bf1, 1, co);
    BAR;
    MMA(0, 1, bf1);
    asm volatile("s_waitcnt vmcnt(0)" ::: "memory");  // A1(15) landed
    BAR;
    LDA(1, co);
    BAR;
    MMA(1, 0, bf0);
    BAR;
    MMA(1, 1, bf1);
    BAR;  // publish: all LDS reads done before epilogue reuses smem
  }
#undef MMA
#undef LDB
#undef LDA
#undef STG
#undef BAR
#undef FENCE
}

// ---------------------------------------------------------------------------
// QKV projection, 256x256 tiles. grid 384 (XCD-swizzled), block 512.
// ---------------------------------------------------------------------------
__global__ __launch_bounds__(512, 2) void qkv256_kernel(
    const ushort_t* __restrict__ Abf, const ushort_t* __restrict__ Wt,
    const float* __restrict__ Bias, ushort_t* __restrict__ Qh,
    ushort_t* __restrict__ Kh, ushort_t* __restrict__ Vh) {
  __shared__ __align__(16) ushort_t smem[65536];  // 128 KiB
  const int bid = blockIdx.x;
  const int sw = (bid & 7) * 48 + (bid >> 3);  // XCD-bijective (384 % 8 == 0)
  const int z = sw >> 7;                       // 0..2
  const int tt = sw & 127;                     // 32 m-tiles x 4 n-tiles
  const int m0 = (tt >> 2) * 256, n0 = (tt & 3) * 256;
  const ushort_t* A = Abf + (size_t)z * (8192 * (size_t)DMODEL);
  const ushort_t* B = Wt + (size_t)z * (DMODEL * (size_t)DMODEL);

  floatx4 acc[8][4] = {};
  gemm256_core(A, B, m0, n0, smem, acc);

  const int tid = threadIdx.x;
  const int w = tid >> 6, l = tid & 63;
  const int wr = w >> 2, wc = w & 3;
  const int lm = l & 15, lg = l >> 4;
  const int lr8 = l >> 3, lc8 = l & 7;
  ushort_t* dst = z == 0 ? Qh : z == 1 ? Kh : Vh;

  ushort_t* ep = smem + w * 8192;  // per-wave 16 KiB scratch
  const int n_base = n0 + wc * 64;
#pragma unroll
  for (int nf = 0; nf < 4; ++nf) {
    const int c = nf * 16 + lm;
    const float bval = Bias[z * DMODEL + n_base + c];
#pragma unroll
    for (int mf = 0; mf < 8; ++mf)
#pragma unroll
      for (int r = 0; r < 4; ++r) {
        const int rowt = mf * 16 + lg * 4 + r;
        ep[rowt * 64 + ((((c >> 3) ^ (rowt & 7)) << 3) | (c & 7))] =
            f2b(acc[mf][nf][r] + bval);
      }
  }
  const int mg = m0 + wr * 128;
  const int b_ = mg >> 11, s_base = mg & (S_LEN - 1);
  const int h_ = n_base >> 6;
  ushort_t* dstb = dst + (((size_t)(b_ * NHEAD + h_) * S_LEN + s_base) << 6);
#pragma unroll
  for (int i = 0; i < 16; ++i) {
    const int row = lr8 + 8 * i;
    const short8 v2 = *(const short8*)&ep[row * 64 + ((lc8 ^ lr8) << 3)];
    *(short8*)(dstb + ((size_t)row << 6) + lc8 * 8) = v2;
  }
}

// ---------------------------------------------------------------------------
// QKV projection GEMM  [FALLBACK PATH, small ws]
// ---------------------------------------------------------------------------
__global__ __launch_bounds__(256) void qkv_kernel(
    const void* __restrict__ qin, const void* __restrict__ kin,
    const void* __restrict__ vin, const ushort_t* __restrict__ Wt,
    const float* __restrict__ Bias, const int* __restrict__ flag,
    ushort_t* __restrict__ Qh, ushort_t* __restrict__ Kh,
    ushort_t* __restrict__ Vh) {
  const int z = blockIdx.z;
  const void* A = z == 0 ? qin : z == 1 ? kin : vin;
  const ushort_t* W = Wt + (size_t)z * (DMODEL * (size_t)DMODEL);
  ushort_t* dst = z == 0 ? Qh : z == 1 ? Kh : Vh;
  const int isbf = *flag;

  __shared__ __align__(16) ushort_t smem[2 * 128 * 64];
  ushort_t* As = smem;
  ushort_t* Bs = smem + 128 * 64;

  const int tid = threadIdx.x;
  const int w = tid >> 6, l = tid & 63;
  const int m0 = blockIdx.x * 128, n0 = blockIdx.y * 128;

  floatx4 acc[4][4] = {};

  const int lr8 = l >> 3, lc8 = l & 7;
  const int gblk = lc8 ^ lr8;
  const ushort_t* Agb =
      (const ushort_t*)A + (size_t)(m0 + w * 32 + lr8) * DMODEL + gblk * 8;
  const float* Agf =
      (const float*)A + (size_t)(m0 + w * 32 + (l >> 4)) * DMODEL + (l & 15) * 4;
  const ushort_t* Bg = W + (size_t)(n0 + w * 32 + lr8) * DMODEL + gblk * 8;
  ushort_t* Asw = As + (w * 32) * 64;
  ushort_t* Bsw = Bs + (w * 32) * 64;

  const int wm = (w >> 1) * 64, wn = (w & 1) * 64;
  const int lm = l & 15, lg = l >> 4;
  const int swz = lm & 7;
  const int cA0 = ((0 + lg) ^ swz) * 8;
  const int cA1 = ((4 + lg) ^ swz) * 8;

  for (int kt = 0; kt < 16; ++kt) {
    const int ko = kt * 64;
    if (isbf) {
#pragma unroll
      for (int i = 0; i < 4; ++i)
        gld16(Agb + (size_t)(i * 8) * DMODEL + ko, Asw + (i * 8) * 64);
    } else {
#pragma unroll
      for (int i = 0; i < 8; ++i) {
        const floatx4 x = *(const floatx4*)(Agf + (size_t)(i * 4) * DMODEL + ko);
        ushort4v h;
        h[0] = f2b(x.x); h[1] = f2b(x.y); h[2] = f2b(x.z); h[3] = f2b(x.w);
        const int row = i * 4 + (l >> 4);
        const int blk = ((l & 15) >> 1) ^ (row & 7);
        *(ushort4v*)&Asw[row * 64 + blk * 8 + (l & 1) * 4] = h;
      }
    }
#pragma unroll
    for (int i = 0; i < 4; ++i)
      gld16(Bg + (size_t)(i * 8) * DMODEL + ko, Bsw + (i * 8) * 64);
    __syncthreads();
#pragma unroll
    for (int kk = 0; kk < 64; kk += 32) {
      const int ck = kk ? cA1 : cA0;
      short8 af[4], bf[4];
#pragma unroll
      for (int t = 0; t < 4; ++t)
        af[t] = *(const short8*)&As[(wm + t * 16 + lm) * 64 + ck];
#pragma unroll
      for (int t = 0; t < 4; ++t)
        bf[t] = *(const short8*)&Bs[(wn + t * 16 + lm) * 64 + ck];
#pragma unroll
      for (int mt = 0; mt < 4; ++mt)
#pragma unroll
        for (int nt = 0; nt < 4; ++nt)
          acc[mt][nt] = __builtin_amdgcn_mfma_f32_16x16x32_bf16(
              af[mt], bf[nt], acc[mt][nt], 0, 0, 0);
    }
    __syncthreads();
  }

  ushort_t* ep = smem + w * 4096;
#pragma unroll
  for (int nt = 0; nt < 4; ++nt) {
    const int c = nt * 16 + lm;
    const float bval = Bias[z * DMODEL + n0 + wn + c];
#pragma unroll
    for (int mt = 0; mt < 4; ++mt)
#pragma unroll
      for (int r = 0; r < 4; ++r) {
        const int row_t = mt * 16 + lg * 4 + r;
        ep[row_t * 64 + ((((c >> 3) ^ (row_t & 7)) << 3) | (c & 7))] =
            f2b(acc[mt][nt][r] + bval);
      }
  }
  const int mg = m0 + wm;
  const int b_ = mg >> 11, s_base = mg & (S_LEN - 1);
  const int h_ = (n0 + wn) >> 6;
  ushort_t* dstb = dst + (((size_t)(b_ * NHEAD + h_) * S_LEN + s_base) << 6);
#pragma unroll
  for (int i = 0; i < 8; ++i) {
    const int row = lr8 + 8 * i;
    const short8 v = *(const short8*)&ep[row * 64 + ((lc8 ^ lr8) << 3)];
    *(short8*)(dstb + (size_t)row * 64 + lc8 * 8) = v;
  }
}

// ---------------------------------------------------------------------------
// RoPE in-place over Qh and Kh (contiguous). ROUND-1-EXACT (no Q pre-scale).
// ---------------------------------------------------------------------------
__global__ __launch_bounds__(256) void rope_kernel(ushort_t* __restrict__ QK) {
  const size_t p = (size_t)blockIdx.x * 256 + threadIdx.x;
  const int d2 = (int)(p & 31) * 2;
  const int s = (int)(p >> 5) & (S_LEN - 1);
  const int h = (int)(p >> 16) & (NHEAD - 1);
  const int n = h * HDIM + d2;
  const float freq = exp2f((float)n * (-13.287712379549449f / 1024.0f));
  float sn, cs;
  __sincosf((float)s * freq, &sn, &cs);
  ushort2v v = *(ushort2v*)(QK + 2 * p);
  const float re = b2f(v[0]), im = b2f(v[1]);
  ushort2v o;
  o[0] = f2b(re * cs - im * sn);
  o[1] = f2b(re * sn + im * cs);
  *(ushort2v*)(QK + 2 * p) = o;
}

// ---------------------------------------------------------------------------
// V transpose per (b,h): [s][d] -> [d][s]
// ---------------------------------------------------------------------------
__global__ __launch_bounds__(256) void vtrans_kernel(
    const ushort_t* __restrict__ V, ushort_t* __restrict__ Vt) {
  __shared__ ushort_t t[32][34];
  const int bh = blockIdx.z;
  const int s0 = blockIdx.x * 32, d0 = blockIdx.y * 32;
  const ushort_t* src = V + (size_t)bh * S_LEN * HDIM;
  ushort_t* dst = Vt + (size_t)bh * S_LEN * HDIM;
  const int tx = threadIdx.x & 31, ty = threadIdx.x >> 5;
#pragma unroll
  for (int i = 0; i < 4; ++i)
    t[ty + 8 * i][tx] = src[(size_t)(s0 + ty + 8 * i) * HDIM + d0 + tx];
  __syncthreads();
#pragma unroll
  for (int i = 0; i < 4; ++i)
    dst[(size_t)(d0 + ty + 8 * i) * S_LEN + s0 + tx] = t[tx][ty + 8 * i];
}

// ---------------------------------------------------------------------------
// Flash attention, bf16 MFMA. ROUND-1 STRUCTURE (gld16 staging, stride-72 P,
// rope/Q unchanged). Exactly two arithmetic edits vs round 1, both <=1-ulp
// equivalents of r1's math:
//  (1) p = exp2(S * 0.125*log2e) replaces __expf(S*0.125): one mul + exp
//      instead of two muls + exp. Masked -> exp2(-72.1347) == exp(-50).
//  (2) P bf16 pack via __float2bfloat16 (1 HW cvt) instead of 4-op f2b.
// Row-sum l from an all-ones B-block in the PV MFMA. K/V LDS xor-swizzled.
// grid (16, 64) with XCD-locality swizzle, block 256 (4 waves).
// ---------------------------------------------------------------------------
__global__ __launch_bounds__(256) void attn_kernel(
    const ushort_t* __restrict__ Qh, const ushort_t* __restrict__ Kh,
    const ushort_t* __restrict__ Vt, const int* __restrict__ mask,
    ushort_t* __restrict__ Xa) {
  const int nlin = blockIdx.y * 16 + blockIdx.x;
  const int bh = ((nlin & 7) << 3) | ((nlin >> 3) & 7);
  const int q0 = (nlin >> 6) * 128;
  const int b = bh >> 4, h = bh & 15;
  const int tid = threadIdx.x;
  const int w = tid >> 6, lane = tid & 63;
  const int lm = lane & 15, lg = lane >> 4;

  __shared__ __align__(16) ushort_t Ks[64 * 64];     // K tile [s][d] swizzled
  __shared__ __align__(16) ushort_t Vs[64 * 64];     // V^T tile [d][s] swizzled
  __shared__ __align__(16) ushort_t Ps[4][32 * 72];  // per-wave P [q][s]

  const ushort_t* Qb = Qh + ((size_t)bh * S_LEN + q0 + w * 32) * HDIM;
  const ushort_t* Kb = Kh + (size_t)bh * S_LEN * HDIM;
  const ushort_t* Vb = Vt + (size_t)bh * S_LEN * HDIM;  // [d][s]
  const int* mb = mask + b * S_LEN;

  // Persistent Q fragments (A-layout: m=lm, k=lg*8+j)
  short8 qf[2][2];
#pragma unroll
  for (int mb_ = 0; mb_ < 2; ++mb_)
#pragma unroll
    for (int ks = 0; ks < 2; ++ks)
      qf[mb_][ks] = *(const short8*)(Qb + (size_t)(mb_ * 16 + lm) * HDIM +
                                     ks * 32 + lg * 8);

  // staging: lane (r=lane>>3, blk=lane&7) loads global block blk^r of row r
  const int lr8 = lane >> 3, lc8 = lane & 7;
  const int gblk = lc8 ^ lr8;
  const ushort_t* Kg = Kb + (size_t)(w * 16 + lr8) * HDIM + gblk * 8;
  const ushort_t* Vg = Vb + (size_t)(w * 16 + lr8) * S_LEN + gblk * 8;
  ushort_t* KsW = Ks + (w * 16) * 64;
  ushort_t* VsW = Vs + (w * 16) * 64;

  // swizzled read column offsets: block (ks*4+lg) ^ (row&7), row&7 = lm&7
  const int swz = lm & 7;
  const int cK0 = ((0 + lg) ^ swz) * 8;
  const int cK1 = ((4 + lg) ^ swz) * 8;

  floatx4 Oacc[2][5] = {};  // [mb][nb0..3 = d-blocks, nb4 = row-sum l]

  const short8 ones = {0x3F80, 0x3F80, 0x3F80, 0x3F80,
                       0x3F80, 0x3F80, 0x3F80, 0x3F80};  // bf16 1.0

  for (int j0 = 0; j0 < S_LEN; j0 += 64) {
    __syncthreads();  // previous tile's Ks/Vs reads complete
    gld16(Kg + (size_t)j0 * HDIM, KsW);
    gld16(Kg + (size_t)(j0 + 8) * HDIM, KsW + 8 * 64);
    gld16(Vg + j0, VsW);
    gld16(Vg + (size_t)8 * S_LEN + j0, VsW + 8 * 64);
    int mj[4];
#pragma unroll
    for (int nb = 0; nb < 4; ++nb) mj[nb] = mb[j0 + nb * 16 + lm];
    __syncthreads();  // staging visible

    // ---- S = Q K^T ----
    floatx4 Sacc[2][4] = {};
#pragma unroll
    for (int ks = 0; ks < 2; ++ks) {
      const int ck = ks ? cK1 : cK0;
      short8 kf[4];
#pragma unroll
      for (int nb = 0; nb < 4; ++nb)
        kf[nb] = *(const short8*)&Ks[(nb * 16 + lm) * 64 + ck];
#pragma unroll
      for (int mb_ = 0; mb_ < 2; ++mb_)
#pragma unroll
        for (int nb = 0; nb < 4; ++nb)
          Sacc[mb_][nb] = __builtin_amdgcn_mfma_f32_16x16x32_bf16(
              qf[mb_][ks], kf[nb], Sacc[mb_][nb], 0, 0, 0);
    }

    // ---- p = exp2(S*0.125*log2e)  (== exp(S*0.125)), HW bf16 cvt ----
#pragma unroll
    for (int mb_ = 0; mb_ < 2; ++mb_)
#pragma unroll
      for (int nb = 0; nb < 4; ++nb) {
        const bool mz = (mj[nb] != 0);
#pragma unroll
        for (int r = 0; r < 4; ++r) {
          const float e = mz ? Sacc[mb_][nb][r] * 0.18033688011112042f
                             : -72.13475204444817f;
          Ps[w][(mb_ * 16 + lg * 4 + r) * 72 + nb * 16 + lm] =
              f2b_hw(exp2_fast(e));
        }
      }

    // ---- O += P V, l += P 1  (A = P, B = V^T blocks + ones block) ----
#pragma unroll
    for (int ks = 0; ks < 2; ++ks) {
      const int ck = ks ? cK1 : cK0;
      short8 pf[2], vf[4];
#pragma unroll
      for (int mb_ = 0; mb_ < 2; ++mb_)
        pf[mb_] =
            *(const short8*)&Ps[w][(mb_ * 16 + lm) * 72 + ks * 32 + lg * 8];
#pragma unroll
      for (int nb = 0; nb < 4; ++nb)
        vf[nb] = *(const short8*)&Vs[(nb * 16 + lm) * 64 + ck];
#pragma unroll
      for (int mb_ = 0; mb_ < 2; ++mb_) {
#pragma unroll
        for (int nb = 0; nb < 4; ++nb)
          Oacc[mb_][nb] = __builtin_amdgcn_mfma_f32_16x16x32_bf16(
              pf[mb_], vf[nb], Oacc[mb_][nb], 0, 0, 0);
        Oacc[mb_][4] = __builtin_amdgcn_mfma_f32_16x16x32_bf16(
            pf[mb_], ones, Oacc[mb_][4], 0, 0, 0);
      }
    }
  }

  // ---- epilogue: normalize by l (col 4) and store ----
#pragma unroll
  for (int mb_ = 0; mb_ < 2; ++mb_)
#pragma unroll
    for (int r = 0; r < 4; ++r) {
      const float inv = 1.0f / Oacc[mb_][4][r];
      const int q = q0 + w * 32 + mb_ * 16 + lg * 4 + r;
      ushort_t* orow = Xa + (size_t)(b * S_LEN + q) * DMODEL + h * HDIM;
#pragma unroll
      for (int nb = 0; nb < 4; ++nb)
        orow[nb * 16 + lm] = f2b(Oacc[mb_][nb][r] * inv);
    }
}

// ---------------------------------------------------------------------------
// Output projection: bf16 GEMM (swizzled LDS); bf16 out via LDS-repacked
// coalesced stores, fp32 out via scalar stores. grid (64, 8)
// ---------------------------------------------------------------------------
__global__ __launch_bounds__(256) void oproj_kernel(
    const ushort_t* __restrict__ X, const ushort_t* __restrict__ Wt,
    const float* __restrict__ BiasO, const int* __restrict__ flag,
    void* __restrict__ out) {
  const int isbf = *flag;
  __shared__ __align__(16) ushort_t smem[2 * 128 * 64];
  ushort_t* As = smem;
  ushort_t* Bs = smem + 128 * 64;
  const int tid = threadIdx.x;
  const int w = tid >> 6, l = tid & 63;
  const int m0 = blockIdx.x * 128, n0 = blockIdx.y * 128;

  floatx4 acc[4][4] = {};

  const int lr8 = l >> 3, lc8 = l & 7;
  const int gblk = lc8 ^ lr8;
  const ushort_t* Ag =
      X + (size_t)(m0 + w * 32 + lr8) * DMODEL + gblk * 8;
  const ushort_t* Bg =
      Wt + (size_t)(n0 + w * 32 + lr8) * DMODEL + gblk * 8;
  ushort_t* Asw = As + (w * 32) * 64;
  ushort_t* Bsw = Bs + (w * 32) * 64;

  const int wm = (w >> 1) * 64, wn = (w & 1) * 64;
  const int lm = l & 15, lg = l >> 4;
  const int swz = lm & 7;
  const int cA0 = ((0 + lg) ^ swz) * 8;
  const int cA1 = ((4 + lg) ^ swz) * 8;

  for (int kt = 0; kt < 16; ++kt) {
    const int ko = kt * 64;
#pragma unroll
    for (int i = 0; i < 4; ++i) {
      gld16(Ag + (size_t)(i * 8) * DMODEL + ko, Asw + (i * 8) * 64);
      gld16(Bg + (size_t)(i * 8) * DMODEL + ko, Bsw + (i * 8) * 64);
    }
    __syncthreads();
#pragma unroll
    for (int kk = 0; kk < 64; kk += 32) {
      const int ck = kk ? cA1 : cA0;
      short8 af[4], bf[4];
#pragma unroll
      for (int t = 0; t < 4; ++t)
        af[t] = *(const short8*)&As[(wm + t * 16 + lm) * 64 + ck];
#pragma unroll
      for (int t = 0; t < 4; ++t)
        bf[t] = *(const short8*)&Bs[(wn + t * 16 + lm) * 64 + ck];
#pragma unroll
      for (int mt = 0; mt < 4; ++mt)
#pragma unroll
        for (int nt = 0; nt < 4; ++nt)
          acc[mt][nt] = __builtin_amdgcn_mfma_f32_16x16x32_bf16(
              af[mt], bf[nt], acc[mt][nt], 0, 0, 0);
    }
    __syncthreads();
  }

  if (isbf) {
    ushort_t* ep = smem + w * 4096;
#pragma unroll
    for (int nt = 0; nt < 4; ++nt) {
      const int c = nt * 16 + lm;
      const float bval = BiasO[n0 + wn + c];
#pragma unroll
      for (int mt = 0; mt < 4; ++mt)
#pragma unroll
        for (int r = 0; r < 4; ++r) {
          const int row_t = mt * 16 + lg * 4 + r;
          ep[row_t * 64 + ((((c >> 3) ^ (row_t & 7)) << 3) | (c & 7))] =
              f2b(acc[mt][nt][r] + bval);
        }
    }
    ushort_t* outb = (ushort_t*)out + (size_t)(m0 + wm) * DMODEL + n0 + wn;
#pragma unroll
    for (int i = 0; i < 8; ++i) {
      const int row = lr8 + 8 * i;
      const short8 v = *(const short8*)&ep[row * 64 + ((lc8 ^ lr8) << 3)];
      *(short8*)(outb + (size_t)row * DMODEL + lc8 * 8) = v;
    }
  } else {
    const int lr = lg * 4;
#pragma unroll
    for (int nt = 0; nt < 4; ++nt) {
      const int n_g = n0 + wn + nt * 16 + lm;
      const float bval = BiasO[n_g];
#pragma unroll
      for (int mt = 0; mt < 4; ++mt)
#pragma unroll
        for (int r = 0; r < 4; ++r) {
          const int m_g = m0 + wm + mt * 16 + lr + r;
          ((float*)out)[(size_t)m_g * DMODEL + n_g] = acc[mt][nt][r] + bval;
        }
    }
  }
}

// ---------------------------------------------------------------------------
extern "C" void kernel_launch(void* const* d_in, const int* in_sizes, int n_in,
                              void* d_out, int out_size, void* d_ws,
                              size_t ws_size, hipStream_t stream) {
  char* ws = (char*)d_ws;
  const size_t MB = 1024 * 1024;
  int* flag = (int*)ws;                          // 4 B
  float* Bias = (float*)(ws + 4096);             // 16 KB, [q|k|v|o]
  ushort_t* Wt = (ushort_t*)(ws + 1 * MB);       // 8 MB bf16 (q,k,v,o) n-major
  ushort_t* Qh = (ushort_t*)(ws + 16 * MB);      // 16 MB bf16 [B,H,S,64]
  ushort_t* Kh = (ushort_t*)(ws + 32 * MB);      // 16 MB (contiguous after Qh)
  ushort_t* Vh = (ushort_t*)(ws + 48 * MB);      // 16 MB (dead after vtrans)
  ushort_t* Vt = (ushort_t*)(ws + 64 * MB);      // 16 MB bf16 [B,H,64,S]
  ushort_t* Abf = (ushort_t*)(ws + 80 * MB);     // 48 MB bf16 A (q,k,v)
  ushort_t* Xa = Vh;                             // reuse Vh region [B*S, D]

  const int use256 = ws_size >= (size_t)128 * MB;

  detect_kernel<<<1, 256, 0, stream>>>((const unsigned*)d_in[0], flag);
  bias_kernel<<<16, 256, 0, stream>>>(d_in[4], d_in[6], d_in[8], d_in[10],
                                      flag, Bias);
  wtrans_kernel<<<dim3(32, 32, 4), 256, 0, stream>>>(d_in[3], d_in[5], d_in[7],
                                                     d_in[9], flag, Wt);
  if (use256) {
    convert_kernel<<<dim3(4096, 3), 256, 0, stream>>>(d_in[0], d_in[1],
                                                      d_in[2], flag, Abf);
    qkv256_kernel<<<384, 512, 0, stream>>>(Abf, Wt, Bias, Qh, Kh, Vh);
  } else {
    qkv_kernel<<<dim3(64, 8, 3), 256, 0, stream>>>(d_in[0], d_in[1], d_in[2],
                                                   Wt, Bias, flag, Qh, Kh, Vh);
  }
  rope_kernel<<<32768, 256, 0, stream>>>(Qh);  // covers Qh+Kh (contiguous)
  vtrans_kernel<<<dim3(64, 2, 64), 256, 0, stream>>>(Vh, Vt);
  attn_kernel<<<dim3(16, 64), 256, 0, stream>>>(Qh, Kh, Vt,
                                                (const int*)d_in[11], Xa);
  oproj_kernel<<<dim3(64, 8), 256, 0, stream>>>(
      Xa, Wt + (size_t)3 * DMODEL * DMODEL, Bias + 3 * DMODEL, flag, d_out);
}